// Round 4
// baseline (633.119 us; speedup 1.0000x reference)
//
#include <hip/hip_runtime.h>
#include <hip/hip_bf16.h>

#define N_NODES 100000
#define N_EDGES 600000
#define DIM 128
#define EDIM 32

typedef __attribute__((ext_vector_type(8))) short bf16x8;
typedef __attribute__((ext_vector_type(4))) float f32x4;

static __device__ __forceinline__ short f2bf(float v) {
    __hip_bfloat16 h = __float2bfloat16(v);
    return *(short*)&h;
}

// ---------------- workspace layout (bytes) ----------------
#define AGG_OFF   0ULL                       // N*128 f32 = 51,200,000
#define CSR_OFF   51200000ULL                // E int2   =  4,800,000
#define OFF_OFF   56000000ULL                // N+2 int  =    400,008
#define CUR_OFF   56400008ULL                // N int    =    400,000
#define DEG_OFF   56800008ULL                // N int    =    400,000
#define BSUM_OFF  57200008ULL                // 128 int
#define WS_REQ    57210000ULL
#define SCAN_NBLK 98                         // ceil(100000/1024)

// ===========================================================================
// CSR build
// ===========================================================================
__global__ void count_deg(const int* __restrict__ eidx, int* __restrict__ deg) {
    int e = blockIdx.x * 256 + threadIdx.x;
    if (e < N_EDGES) atomicAdd(&deg[eidx[e]], 1);
}

__global__ __launch_bounds__(1024) void scan_blocks(
    const int* __restrict__ deg, int* __restrict__ off, int* __restrict__ bsum) {
    const int t = blockIdx.x * 1024 + threadIdx.x;
    const int lane = threadIdx.x & 63, wv = threadIdx.x >> 6;
    int v = (t < N_NODES) ? deg[t] : 0;
    int s = v;
    #pragma unroll
    for (int o = 1; o < 64; o <<= 1) {
        int u = __shfl_up(s, o, 64);
        if (lane >= o) s += u;
    }
    __shared__ int wsum[16];
    if (lane == 63) wsum[wv] = s;
    __syncthreads();
    if (threadIdx.x == 0) {
        int a = 0;
        #pragma unroll
        for (int w = 0; w < 16; ++w) { int tmp = wsum[w]; wsum[w] = a; a += tmp; }
        bsum[blockIdx.x] = a;
    }
    __syncthreads();
    if (t < N_NODES) off[t] = s - v + wsum[wv];
}

__global__ void scan_totals(int* __restrict__ bsum) {
    if (threadIdx.x == 0) {
        int a = 0;
        for (int i = 0; i < SCAN_NBLK; ++i) { int t = bsum[i]; bsum[i] = a; a += t; }
    }
}

__global__ __launch_bounds__(1024) void scan_add(int* __restrict__ off, const int* __restrict__ bsum) {
    const int t = blockIdx.x * 1024 + threadIdx.x;
    if (t < N_NODES) off[t] += bsum[blockIdx.x];
}

__global__ void csr_fill(const int* __restrict__ eidx, const int* __restrict__ off,
                         int* __restrict__ cur, int2* __restrict__ csr) {
    int e = blockIdx.x * 256 + threadIdx.x;
    if (e < N_EDGES) {
        int i = eidx[e];
        int p = atomicAdd(&cur[i], 1);
        csr[off[i] + p] = make_int2(e, eidx[N_EDGES + e]);
    }
}

// ===========================================================================
// Aggregate: one wave per node. We columns in regs (64/lane), ea broadcast
// via shfl, register accumulate, single coalesced store. No f32 atomics.
// ===========================================================================
__global__ __launch_bounds__(256) void gine_aggregate(
    const float* __restrict__ x,
    const float* __restrict__ eattr,
    const float* __restrict__ We,
    const float* __restrict__ be,
    const int* __restrict__ off,
    const int* __restrict__ deg,
    const int2* __restrict__ csr,
    float* __restrict__ agg)
{
    const int lane = threadIdx.x & 63;
    const int gw = (blockIdx.x * 256 + threadIdx.x) >> 6;
    const int nw = (gridDim.x * 256) >> 6;

    float we0[EDIM], we1[EDIM];
    #pragma unroll
    for (int k = 0; k < EDIM; ++k) {
        we0[k] = We[k * DIM + lane];
        we1[k] = We[k * DIM + 64 + lane];
    }
    const float be0 = be[lane], be1 = be[64 + lane];

    for (int n = gw; n < N_NODES; n += nw) {
        const int s = off[n], dg = deg[n];
        float a0 = dg * be0, a1 = dg * be1;
        if (dg > 0) {
            int2 c = csr[s];
            float eav = (lane < 32) ? eattr[(size_t)c.x * EDIM + lane] : 0.f;
            float x0 = x[(size_t)c.y * DIM + lane];
            float x1 = x[(size_t)c.y * DIM + 64 + lane];
            for (int t = 0; t < dg; ++t) {
                float neav = 0.f, nx0 = 0.f, nx1 = 0.f;
                const bool more = (t + 1 < dg);
                if (more) {           // depth-1 prefetch of next edge
                    int2 cn = csr[s + t + 1];
                    neav = (lane < 32) ? eattr[(size_t)cn.x * EDIM + lane] : 0.f;
                    nx0 = x[(size_t)cn.y * DIM + lane];
                    nx1 = x[(size_t)cn.y * DIM + 64 + lane];
                }
                a0 += x0; a1 += x1;
                #pragma unroll
                for (int k = 0; k < EDIM; ++k) {
                    float ev = __shfl(eav, k, 64);
                    a0 += ev * we0[k];
                    a1 += ev * we1[k];
                }
                eav = neav; x0 = nx0; x1 = nx1;
            }
        }
        agg[(size_t)n * DIM + lane] = a0;
        agg[(size_t)n * DIM + 64 + lane] = a1;
    }
}

// ===========================================================================
// Fallback edge kernel (atomics) if ws too small for CSR. We in regs, 8.5 KB LDS.
// ===========================================================================
__global__ __launch_bounds__(128) void gine_edge_atomic(
    const float* __restrict__ x,
    const int* __restrict__ eidx,
    const float* __restrict__ eattr,
    const float* __restrict__ We,
    const float* __restrict__ be,
    float* __restrict__ agg)
{
    __shared__ float ea_s[64 * EDIM];    // 8 KB
    __shared__ int ii_s[64], jj_s[64];
    const int tid = threadIdx.x;

    float we_r[EDIM];
    #pragma unroll
    for (int k = 0; k < EDIM; ++k) we_r[k] = We[k * DIM + tid];
    const float be_d = be[tid];

    const int e0 = blockIdx.x * 64;
    const int nE = min(64, N_EDGES - e0);
    const float4* ea_g = (const float4*)(eattr + (size_t)e0 * EDIM);
    for (int r = tid; r < nE * 8; r += 128) ((float4*)ea_s)[r] = ea_g[r];
    if (tid < nE) {
        ii_s[tid] = eidx[e0 + tid];
        jj_s[tid] = eidx[N_EDGES + e0 + tid];
    }
    __syncthreads();

    for (int t = 0; t < nE; ++t) {
        float acc = be_d + x[(size_t)jj_s[t] * DIM + tid];
        const float4* ea = (const float4*)&ea_s[t * EDIM];
        #pragma unroll
        for (int k4 = 0; k4 < 8; ++k4) {
            float4 e = ea[k4];
            acc += e.x * we_r[k4 * 4 + 0];
            acc += e.y * we_r[k4 * 4 + 1];
            acc += e.z * we_r[k4 * 4 + 2];
            acc += e.w * we_r[k4 * 4 + 3];
        }
        atomicAdd(&agg[(size_t)ii_s[t] * DIM + tid], acc);
    }
}

// ===========================================================================
// Fused MLP1 + MLP2 + LayerNorm (bf16 MFMA 16x16x32).
// 1024 threads = 16 waves share the 64 KB W-fragment cache -> 50% occupancy.
// ===========================================================================
#define HROW_STRIDE 136

__global__ __launch_bounds__(1024) void gine_mlp_fused(
    const float* __restrict__ x,
    const float* __restrict__ agg,
    const float* __restrict__ W1,
    const float* __restrict__ b1,
    const float* __restrict__ W2,
    const float* __restrict__ b2,
    const float* __restrict__ epsp,
    const float* __restrict__ gamma,
    const float* __restrict__ beta,
    float* __restrict__ out)
{
    __shared__ short Wp[2][16384];               // 64 KB
    __shared__ short hrow[16][16 * HROW_STRIDE]; // 68 KB

    const int tid  = threadIdx.x;
    const int wave = tid >> 6;
    const int lane = tid & 63;
    const int m    = lane & 15;
    const int g    = lane >> 4;

    // pack W1/W2 B-fragments: Wp[l][s*64+lane] = B[k=kc*32+g*8+j][n=dt*16+m]
    for (int s = wave * 2; s < wave * 2 + 2; ++s) {
        const int dt = s >> 2, kc = s & 3;
        const int krow = kc * 32 + g * 8;
        const int col  = dt * 16 + m;
        short p1[8], p2[8];
        #pragma unroll
        for (int j = 0; j < 8; ++j) {
            p1[j] = f2bf(W1[(size_t)(krow + j) * DIM + col]);
            p2[j] = f2bf(W2[(size_t)(krow + j) * DIM + col]);
        }
        #pragma unroll
        for (int j = 0; j < 8; ++j) {
            Wp[0][(s * 64 + lane) * 8 + j] = p1[j];
            Wp[1][(s * 64 + lane) * 8 + j] = p2[j];
        }
    }

    float b1v[8], b2v[8], gv[8], btv[8];
    #pragma unroll
    for (int dt = 0; dt < 8; ++dt) {
        const int d = dt * 16 + m;
        b1v[dt] = b1[d]; b2v[dt] = b2[d]; gv[dt] = gamma[d]; btv[dt] = beta[d];
    }
    const float epv = 1.0f + epsp[0];
    __syncthreads();

    short* myrow = &hrow[wave][0];
    const int ntiles = N_NODES / 16;             // 6250

    for (int tile = blockIdx.x * 16 + wave; tile < ntiles; tile += gridDim.x * 16) {
        const int nbase = tile * 16;

        #pragma unroll
        for (int r = 0; r < 8; ++r) {
            const int idx4 = r * 64 + lane;
            const int node = idx4 >> 5, dq = idx4 & 31;
            const size_t goff = ((size_t)(nbase + node) * DIM + dq * 4) / 4;
            float4 xv = ((const float4*)x)[goff];
            float4 av = ((const float4*)agg)[goff];
            short4 hv;
            hv.x = f2bf(epv * xv.x + av.x);
            hv.y = f2bf(epv * xv.y + av.y);
            hv.z = f2bf(epv * xv.z + av.z);
            hv.w = f2bf(epv * xv.w + av.w);
            *(short4*)&myrow[node * HROW_STRIDE + dq * 4] = hv;
        }
        __asm__ volatile("s_waitcnt lgkmcnt(0)" ::: "memory");

        f32x4 acc[8];
        #pragma unroll
        for (int dt = 0; dt < 8; ++dt) acc[dt] = (f32x4){0.f, 0.f, 0.f, 0.f};
        #pragma unroll
        for (int kc = 0; kc < 4; ++kc) {
            bf16x8 afrag = *(bf16x8*)&myrow[m * HROW_STRIDE + kc * 32 + g * 8];
            #pragma unroll
            for (int dt = 0; dt < 8; ++dt) {
                bf16x8 bfrag = *(bf16x8*)&Wp[0][((dt * 4 + kc) * 64 + lane) * 8];
                acc[dt] = __builtin_amdgcn_mfma_f32_16x16x32_bf16(afrag, bfrag, acc[dt], 0, 0, 0);
            }
        }
        __asm__ volatile("s_waitcnt lgkmcnt(0)" ::: "memory");

        #pragma unroll
        for (int dt = 0; dt < 8; ++dt)
            #pragma unroll
            for (int q = 0; q < 4; ++q) {
                float v = fmaxf(acc[dt][q] + b1v[dt], 0.f);
                myrow[(g * 4 + q) * HROW_STRIDE + dt * 16 + m] = f2bf(v);
            }
        __asm__ volatile("s_waitcnt lgkmcnt(0)" ::: "memory");

        #pragma unroll
        for (int dt = 0; dt < 8; ++dt) acc[dt] = (f32x4){0.f, 0.f, 0.f, 0.f};
        #pragma unroll
        for (int kc = 0; kc < 4; ++kc) {
            bf16x8 afrag = *(bf16x8*)&myrow[m * HROW_STRIDE + kc * 32 + g * 8];
            #pragma unroll
            for (int dt = 0; dt < 8; ++dt) {
                bf16x8 bfrag = *(bf16x8*)&Wp[1][((dt * 4 + kc) * 64 + lane) * 8];
                acc[dt] = __builtin_amdgcn_mfma_f32_16x16x32_bf16(afrag, bfrag, acc[dt], 0, 0, 0);
            }
        }

        float s[4] = {0, 0, 0, 0}, ss[4] = {0, 0, 0, 0};
        #pragma unroll
        for (int dt = 0; dt < 8; ++dt)
            #pragma unroll
            for (int q = 0; q < 4; ++q) {
                float o = acc[dt][q] + b2v[dt];
                acc[dt][q] = o;
                s[q] += o; ss[q] += o * o;
            }
        #pragma unroll
        for (int mask = 1; mask < 16; mask <<= 1)
            #pragma unroll
            for (int q = 0; q < 4; ++q) {
                s[q]  += __shfl_xor(s[q], mask, 64);
                ss[q] += __shfl_xor(ss[q], mask, 64);
            }
        float mu[4], inv[4];
        #pragma unroll
        for (int q = 0; q < 4; ++q) {
            mu[q] = s[q] * (1.0f / DIM);
            float var = ss[q] * (1.0f / DIM) - mu[q] * mu[q];
            inv[q] = rsqrtf(var + 1e-5f);
        }
        #pragma unroll
        for (int dt = 0; dt < 8; ++dt)
            #pragma unroll
            for (int q = 0; q < 4; ++q) {
                const int node = nbase + g * 4 + q;
                out[(size_t)node * DIM + dt * 16 + m] =
                    (acc[dt][q] - mu[q]) * inv[q] * gv[dt] + btv[dt];
            }
    }
}

extern "C" void kernel_launch(void* const* d_in, const int* in_sizes, int n_in,
                              void* d_out, int out_size, void* d_ws, size_t ws_size,
                              hipStream_t stream) {
    const float* x     = (const float*)d_in[0];
    const int*   eidx  = (const int*)d_in[1];
    const float* eattr = (const float*)d_in[2];
    const float* We    = (const float*)d_in[3];
    const float* be    = (const float*)d_in[4];
    const float* W1    = (const float*)d_in[5];
    const float* b1    = (const float*)d_in[6];
    const float* W2    = (const float*)d_in[7];
    const float* b2v   = (const float*)d_in[8];
    const float* eps   = (const float*)d_in[9];
    const float* gamma = (const float*)d_in[10];
    const float* beta  = (const float*)d_in[11];
    float* out = (float*)d_out;

    char* ws = (char*)d_ws;
    float* agg = (float*)(ws + AGG_OFF);

    if (ws_size >= WS_REQ) {
        int2* csr  = (int2*)(ws + CSR_OFF);
        int*  off  = (int*)(ws + OFF_OFF);
        int*  cur  = (int*)(ws + CUR_OFF);
        int*  deg  = (int*)(ws + DEG_OFF);
        int*  bsum = (int*)(ws + BSUM_OFF);

        hipMemsetAsync(cur, 0, 800000, stream);   // covers cur + deg (adjacent)
        count_deg<<<(N_EDGES + 255) / 256, 256, 0, stream>>>(eidx, deg);
        scan_blocks<<<SCAN_NBLK, 1024, 0, stream>>>(deg, off, bsum);
        scan_totals<<<1, 64, 0, stream>>>(bsum);
        scan_add<<<SCAN_NBLK, 1024, 0, stream>>>(off, bsum);
        csr_fill<<<(N_EDGES + 255) / 256, 256, 0, stream>>>(eidx, off, cur, csr);
        gine_aggregate<<<2048, 256, 0, stream>>>(x, eattr, We, be, off, deg, csr, agg);
    } else {
        hipMemsetAsync(agg, 0, (size_t)N_NODES * DIM * sizeof(float), stream);
        gine_edge_atomic<<<(N_EDGES + 63) / 64, 128, 0, stream>>>(x, eidx, eattr, We, be, agg);
    }

    gine_mlp_fused<<<256, 1024, 0, stream>>>(x, agg, W1, b1, W2, b2v, eps, gamma, beta, out);
}

// Round 6
// 354.845 us; speedup vs baseline: 1.7842x; 1.7842x over previous
//
#include <hip/hip_runtime.h>
#include <hip/hip_bf16.h>

#define N_NODES 100000
#define N_EDGES 600000
#define DIM 128
#define EDIM 32

typedef __attribute__((ext_vector_type(8))) short bf16x8;
typedef __attribute__((ext_vector_type(4))) float f32x4;

static __device__ __forceinline__ short f2bf(float v) {
    __hip_bfloat16 h = __float2bfloat16(v);
    return *(short*)&h;
}
static __device__ __forceinline__ float bfu2f(unsigned short u) {
    return __uint_as_float(((unsigned int)u) << 16);
}

// ---------------- workspace layout (bytes) ----------------
#define AGGX_OFF  0ULL                       // bf16 N*128 = 25,600,000
#define AGGE_OFF  25600000ULL                // bf16 N*32  =  6,400,000
#define CSR_OFF   32000000ULL                // int2 E     =  4,800,000
#define OFF_OFF   36800000ULL                // int  N+1
#define DEG_OFF   37200008ULL                // int  N
#define BSUM_OFF  37600016ULL                // int  128
#define WEW1_OFF  37600528ULL                // f32  32*128 = 16,384
#define SCAN_NBLK 98                         // ceil(100000/1024)

// ===========================================================================
// WeW1 = We @ W1  (32x128 f32). The aggE@We term enters layer 1 as
// aggE @ (We @ W1) by linearity (ReLU is applied after the full sum).
// ===========================================================================
__global__ __launch_bounds__(1024) void compute_wew1(
    const float* __restrict__ We, const float* __restrict__ W1,
    float* __restrict__ wew1) {
    const int idx = blockIdx.x * 1024 + threadIdx.x;   // 4 blocks -> 4096
    const int k = idx >> 7, d2 = idx & 127;
    float a = 0.f;
    #pragma unroll 8
    for (int d = 0; d < DIM; ++d)
        a += We[k * DIM + d] * W1[d * DIM + d2];       // We: uniform; W1: coalesced
    wew1[k * DIM + d2] = a;
}

// ===========================================================================
// CSR build
// ===========================================================================
__global__ void count_deg(const int* __restrict__ eidx, int* __restrict__ deg) {
    int e = blockIdx.x * 256 + threadIdx.x;
    if (e < N_EDGES) atomicAdd(&deg[eidx[e]], 1);
}

__global__ __launch_bounds__(1024) void scan_blocks(
    const int* __restrict__ deg, int* __restrict__ off, int* __restrict__ bsum) {
    const int t = blockIdx.x * 1024 + threadIdx.x;
    const int lane = threadIdx.x & 63, wv = threadIdx.x >> 6;
    int v = (t < N_NODES) ? deg[t] : 0;
    int s = v;
    #pragma unroll
    for (int o = 1; o < 64; o <<= 1) {
        int u = __shfl_up(s, o, 64);
        if (lane >= o) s += u;
    }
    __shared__ int wsum[16];
    if (lane == 63) wsum[wv] = s;
    __syncthreads();
    if (threadIdx.x == 0) {
        int a = 0;
        #pragma unroll
        for (int w = 0; w < 16; ++w) { int tmp = wsum[w]; wsum[w] = a; a += tmp; }
        bsum[blockIdx.x] = a;
    }
    __syncthreads();
    if (t < N_NODES) off[t] = s - v + wsum[wv];
}

__global__ void scan_totals(int* __restrict__ bsum) {
    if (threadIdx.x == 0) {
        int a = 0;
        for (int i = 0; i < SCAN_NBLK; ++i) { int t = bsum[i]; bsum[i] = a; a += t; }
    }
}

__global__ __launch_bounds__(1024) void scan_add(int* __restrict__ off, const int* __restrict__ bsum) {
    const int t = blockIdx.x * 1024 + threadIdx.x;
    if (t < N_NODES) off[t] += bsum[blockIdx.x];
}

// fill using off itself as the cursor: afterwards off[i] = segment END.
__global__ void csr_fill(const int* __restrict__ eidx, int* __restrict__ off,
                         int2* __restrict__ csr) {
    int e = blockIdx.x * 256 + threadIdx.x;
    if (e < N_EDGES) {
        int i = eidx[e];
        int p = atomicAdd(&off[i], 1);
        csr[p] = make_int2(e, eidx[N_EDGES + e]);
    }
}

// ===========================================================================
// Aggregate (linearity-exploiting): per node sum raw x rows and raw ea rows.
// aggX[n] = sum x[j_e] (128, bf16); aggE[n] = sum ea[e] (32, bf16).
// Wave per node; gathers batched 8 edges -> ~24 outstanding loads.
// ===========================================================================
__global__ __launch_bounds__(256) void gine_aggregate(
    const float* __restrict__ x,
    const float* __restrict__ eattr,
    const int* __restrict__ off_end,
    const int* __restrict__ deg,
    const int2* __restrict__ csr,
    unsigned short* __restrict__ aggX,
    unsigned short* __restrict__ aggE)
{
    const int lane = threadIdx.x & 63;
    const int gw = (blockIdx.x * 256 + threadIdx.x) >> 6;
    const int nw = (gridDim.x * 256) >> 6;

    for (int n = gw; n < N_NODES; n += nw) {
        const int dg = deg[n];
        const int s = off_end[n] - dg;
        float a0 = 0.f, a1 = 0.f, ae = 0.f;

        for (int t0 = 0; t0 < dg; t0 += 8) {
            const int c = min(8, dg - t0);          // wave-uniform
            int ei[8], ji[8];
            #pragma unroll
            for (int k = 0; k < 8; ++k)
                if (k < c) { int2 cc = csr[s + t0 + k]; ei[k] = cc.x; ji[k] = cc.y; }
            float xv0[8], xv1[8], ev[8];
            #pragma unroll
            for (int k = 0; k < 8; ++k)
                if (k < c) {
                    xv0[k] = x[(size_t)ji[k] * DIM + lane];
                    xv1[k] = x[(size_t)ji[k] * DIM + 64 + lane];
                    ev[k]  = (lane < 32) ? eattr[(size_t)ei[k] * EDIM + lane] : 0.f;
                }
            #pragma unroll
            for (int k = 0; k < 8; ++k)
                if (k < c) { a0 += xv0[k]; a1 += xv1[k]; ae += ev[k]; }
        }
        aggX[(size_t)n * DIM + lane]      = (unsigned short)f2bf(a0);
        aggX[(size_t)n * DIM + 64 + lane] = (unsigned short)f2bf(a1);
        if (lane < 32) aggE[(size_t)n * EDIM + lane] = (unsigned short)f2bf(ae);
    }
}

// ===========================================================================
// Fused (aggE@WeW1) + MLP1 + MLP2 + LayerNorm, bf16 MFMA 16x16x32.
// hrow = (1+eps)*x + aggX + deg*be; layer1 = hrow@W1 + aggE@(We@W1).
// 1024 threads = 16 waves share W-fragment LDS caches.
// ===========================================================================
#define HROW_STRIDE 136

__global__ __launch_bounds__(1024) void gine_mlp_fused(
    const float* __restrict__ x,
    const unsigned short* __restrict__ aggX,
    const unsigned short* __restrict__ aggE,
    const int* __restrict__ deg,
    const float* __restrict__ wew1,
    const float* __restrict__ be,
    const float* __restrict__ W1,
    const float* __restrict__ b1,
    const float* __restrict__ W2,
    const float* __restrict__ b2,
    const float* __restrict__ epsp,
    const float* __restrict__ gamma,
    const float* __restrict__ beta,
    float* __restrict__ out)
{
    __shared__ short Wp[2][16384];               // 64 KB  W1/W2 B-fragments
    __shared__ short Wep[4096];                  //  8 KB  WeW1 B-fragments (K=32)
    __shared__ short hrow[16][16 * HROW_STRIDE]; // 68 KB  per-wave node rows

    const int tid  = threadIdx.x;
    const int wave = tid >> 6;
    const int lane = tid & 63;
    const int m    = lane & 15;
    const int g    = lane >> 4;

    // pack W1/W2 B-fragments: Wp[l][s*64+lane] = B[k=kc*32+g*8+j][n=dt*16+m]
    for (int s = wave * 2; s < wave * 2 + 2; ++s) {
        const int dt = s >> 2, kc = s & 3;
        const int krow = kc * 32 + g * 8;
        const int col  = dt * 16 + m;
        short p1[8], p2[8];
        #pragma unroll
        for (int j = 0; j < 8; ++j) {
            p1[j] = f2bf(W1[(size_t)(krow + j) * DIM + col]);
            p2[j] = f2bf(W2[(size_t)(krow + j) * DIM + col]);
        }
        #pragma unroll
        for (int j = 0; j < 8; ++j) {
            Wp[0][(s * 64 + lane) * 8 + j] = p1[j];
            Wp[1][(s * 64 + lane) * 8 + j] = p2[j];
        }
    }
    // pack WeW1 B-fragments (K=32): Wep[dt*64+lane] = WeW1[k=g*8+j][n=dt*16+m]
    if (wave < 8) {
        const int dt = wave;
        const int col = dt * 16 + m;
        short pw[8];
        #pragma unroll
        for (int j = 0; j < 8; ++j) pw[j] = f2bf(wew1[(size_t)(g * 8 + j) * DIM + col]);
        #pragma unroll
        for (int j = 0; j < 8; ++j) Wep[(dt * 64 + lane) * 8 + j] = pw[j];
    }

    float b1v[8], b2v[8], gv[8], btv[8];
    #pragma unroll
    for (int dt = 0; dt < 8; ++dt) {
        const int d = dt * 16 + m;
        b1v[dt] = b1[d]; b2v[dt] = b2[d]; gv[dt] = gamma[d]; btv[dt] = beta[d];
    }
    const float epv = 1.0f + epsp[0];
    __syncthreads();

    short* myrow = &hrow[wave][0];
    const int ntiles = N_NODES / 16;             // 6250

    for (int tile = blockIdx.x * 16 + wave; tile < ntiles; tile += gridDim.x * 16) {
        const int nbase = tile * 16;

        // A-fragment of aggE: lane(m,g) takes aggE[nbase+m][g*8 .. g*8+8)
        bf16x8 afragE = *(const bf16x8*)&aggE[(size_t)(nbase + m) * EDIM + g * 8];

        // stage hrow = (1+eps)*x + aggX + deg*be as bf16 rows [16][128]
        #pragma unroll
        for (int r = 0; r < 8; ++r) {
            const int idx4 = r * 64 + lane;          // 512 quads = 16 nodes x 32
            const int node = idx4 >> 5, dq = idx4 & 31;
            const size_t goff = (size_t)(nbase + node) * DIM + dq * 4;
            float4 xv = *(const float4*)&x[goff];
            ushort4 au = *(const ushort4*)&aggX[goff];
            float4 bev = ((const float4*)be)[dq];
            float dgf = (float)deg[nbase + node];
            short4 hv;
            hv.x = f2bf(epv * xv.x + bfu2f(au.x) + dgf * bev.x);
            hv.y = f2bf(epv * xv.y + bfu2f(au.y) + dgf * bev.y);
            hv.z = f2bf(epv * xv.z + bfu2f(au.z) + dgf * bev.z);
            hv.w = f2bf(epv * xv.w + bfu2f(au.w) + dgf * bev.w);
            *(short4*)&myrow[node * HROW_STRIDE + dq * 4] = hv;
        }
        __asm__ volatile("s_waitcnt lgkmcnt(0)" ::: "memory");

        // layer 1 = aggE@WeW1 (K=32 chunk) + hrow@W1 (K=128)
        f32x4 acc[8];
        #pragma unroll
        for (int dt = 0; dt < 8; ++dt) {
            bf16x8 bfrag = *(bf16x8*)&Wep[(dt * 64 + lane) * 8];
            acc[dt] = __builtin_amdgcn_mfma_f32_16x16x32_bf16(
                afragE, bfrag, (f32x4){0.f, 0.f, 0.f, 0.f}, 0, 0, 0);
        }
        #pragma unroll
        for (int kc = 0; kc < 4; ++kc) {
            bf16x8 afrag = *(bf16x8*)&myrow[m * HROW_STRIDE + kc * 32 + g * 8];
            #pragma unroll
            for (int dt = 0; dt < 8; ++dt) {
                bf16x8 bfrag = *(bf16x8*)&Wp[0][((dt * 4 + kc) * 64 + lane) * 8];
                acc[dt] = __builtin_amdgcn_mfma_f32_16x16x32_bf16(afrag, bfrag, acc[dt], 0, 0, 0);
            }
        }
        __asm__ volatile("s_waitcnt lgkmcnt(0)" ::: "memory");

        // relu(acc + b1) -> myrow (C-layout: node=g*4+q, dim=dt*16+m)
        #pragma unroll
        for (int dt = 0; dt < 8; ++dt)
            #pragma unroll
            for (int q = 0; q < 4; ++q) {
                float v = fmaxf(acc[dt][q] + b1v[dt], 0.f);
                myrow[(g * 4 + q) * HROW_STRIDE + dt * 16 + m] = f2bf(v);
            }
        __asm__ volatile("s_waitcnt lgkmcnt(0)" ::: "memory");

        // layer 2
        #pragma unroll
        for (int dt = 0; dt < 8; ++dt) acc[dt] = (f32x4){0.f, 0.f, 0.f, 0.f};
        #pragma unroll
        for (int kc = 0; kc < 4; ++kc) {
            bf16x8 afrag = *(bf16x8*)&myrow[m * HROW_STRIDE + kc * 32 + g * 8];
            #pragma unroll
            for (int dt = 0; dt < 8; ++dt) {
                bf16x8 bfrag = *(bf16x8*)&Wp[1][((dt * 4 + kc) * 64 + lane) * 8];
                acc[dt] = __builtin_amdgcn_mfma_f32_16x16x32_bf16(afrag, bfrag, acc[dt], 0, 0, 0);
            }
        }

        // bias + LayerNorm. Lane holds (dt,q): node g*4+q, dim dt*16+m.
        float s[4] = {0, 0, 0, 0}, ss[4] = {0, 0, 0, 0};
        #pragma unroll
        for (int dt = 0; dt < 8; ++dt)
            #pragma unroll
            for (int q = 0; q < 4; ++q) {
                float o = acc[dt][q] + b2v[dt];
                acc[dt][q] = o;
                s[q] += o; ss[q] += o * o;
            }
        #pragma unroll
        for (int mask = 1; mask < 16; mask <<= 1)
            #pragma unroll
            for (int q = 0; q < 4; ++q) {
                s[q]  += __shfl_xor(s[q], mask, 64);
                ss[q] += __shfl_xor(ss[q], mask, 64);
            }
        float mu[4], inv[4];
        #pragma unroll
        for (int q = 0; q < 4; ++q) {
            mu[q] = s[q] * (1.0f / DIM);
            float var = ss[q] * (1.0f / DIM) - mu[q] * mu[q];
            inv[q] = rsqrtf(var + 1e-5f);
        }
        #pragma unroll
        for (int dt = 0; dt < 8; ++dt)
            #pragma unroll
            for (int q = 0; q < 4; ++q) {
                const int node = nbase + g * 4 + q;
                out[(size_t)node * DIM + dt * 16 + m] =
                    (acc[dt][q] - mu[q]) * inv[q] * gv[dt] + btv[dt];
            }
    }
}

extern "C" void kernel_launch(void* const* d_in, const int* in_sizes, int n_in,
                              void* d_out, int out_size, void* d_ws, size_t ws_size,
                              hipStream_t stream) {
    const float* x     = (const float*)d_in[0];
    const int*   eidx  = (const int*)d_in[1];
    const float* eattr = (const float*)d_in[2];
    const float* We    = (const float*)d_in[3];
    const float* be    = (const float*)d_in[4];
    const float* W1    = (const float*)d_in[5];
    const float* b1    = (const float*)d_in[6];
    const float* W2    = (const float*)d_in[7];
    const float* b2v   = (const float*)d_in[8];
    const float* eps   = (const float*)d_in[9];
    const float* gamma = (const float*)d_in[10];
    const float* beta  = (const float*)d_in[11];
    float* out = (float*)d_out;

    char* ws = (char*)d_ws;
    unsigned short* aggX = (unsigned short*)(ws + AGGX_OFF);
    unsigned short* aggE = (unsigned short*)(ws + AGGE_OFF);
    int2*  csr  = (int2*)(ws + CSR_OFF);
    int*   off  = (int*)(ws + OFF_OFF);
    int*   deg  = (int*)(ws + DEG_OFF);
    int*   bsum = (int*)(ws + BSUM_OFF);
    float* wew1 = (float*)(ws + WEW1_OFF);

    hipMemsetAsync(deg, 0, 400000, stream);
    compute_wew1<<<4, 1024, 0, stream>>>(We, W1, wew1);
    count_deg<<<(N_EDGES + 255) / 256, 256, 0, stream>>>(eidx, deg);
    scan_blocks<<<SCAN_NBLK, 1024, 0, stream>>>(deg, off, bsum);
    scan_totals<<<1, 64, 0, stream>>>(bsum);
    scan_add<<<SCAN_NBLK, 1024, 0, stream>>>(off, bsum);
    csr_fill<<<(N_EDGES + 255) / 256, 256, 0, stream>>>(eidx, off, csr);
    gine_aggregate<<<2048, 256, 0, stream>>>(x, eattr, off, deg, csr, aggX, aggE);
    gine_mlp_fused<<<256, 1024, 0, stream>>>(x, aggX, aggE, deg, wew1, be,
                                             W1, b1, W2, b2v, eps, gamma, beta, out);
}